// Round 5
// baseline (375.159 us; speedup 1.0000x reference)
//
#include <hip/hip_runtime.h>

#define TT   512
#define HH   50
#define MB   4            // batch rows per block
#define NW   7            // waves per block
#define NTHR (NW * 64)    // 448 threads

typedef _Float16 f16x8 __attribute__((ext_vector_type(8)));
typedef float    f32x4 __attribute__((ext_vector_type(4)));

#define L2E 1.4426950408889634f

__device__ __forceinline__ float rcp_f(float v) { return __builtin_amdgcn_rcpf(v); }
__device__ __forceinline__ float ex2_f(float v) { return __builtin_amdgcn_exp2f(v); }

// Grid 512 (2 blocks/CU). Wave w owns gate-tiles 2w, 2w+1 (8 units). MFMA cols:
// 0-3 = L0 (B = h0), 4-7 = L1 (B = [h0copy; h1]), 8-15 junk. Lane (q,n):
//   n0-3: L0 tile2w, n4-7: L1 tile2w, n8-11: L0 tile2w+1, n12-15: L1 tile2w+1
// (tile2w+1 quads arrive via shfl_xor 8). One chain per lane, one barrier per step.
// Layer 1 pipelined one step behind layer 0.
__global__ __launch_bounds__(NTHR, 4)
void lstm2_kernel(const float* __restrict__ x,
                  const float* __restrict__ W_ih0, const float* __restrict__ W_hh0,
                  const float* __restrict__ b_ih0, const float* __restrict__ b_hh0,
                  const float* __restrict__ W_ih1, const float* __restrict__ W_hh1,
                  const float* __restrict__ b_ih1, const float* __restrict__ b_hh1,
                  const float* __restrict__ W_fc,  const float* __restrict__ b_fc,
                  float* __restrict__ out)
{
    // h layout [parity][ki][q][col][e]; unit u -> (ki=u>>5, q=(u>>3)&3, e=u&7).
    __shared__ __align__(16) _Float16 sh0[2][2][4][16][8];   // h0: cols 0-3 and copy at 4-7
    __shared__ __align__(16) _Float16 sh1[2][2][4][16][8];   // h1: cols 4-7 real
    __shared__ float sh_x[MB][TT + 4];
    __shared__ float shf[MB][52];
    __shared__ float sh_wfc[HH];

    const int tid = threadIdx.x;
    const int w   = tid >> 6;
    const int l   = tid & 63;
    const int q   = l >> 4;
    const int n   = l & 15;
    const int b0  = blockIdx.x * MB;

    for (int i = tid; i < 2 * 2 * 4 * 16 * 8; i += NTHR) {
        (&sh0[0][0][0][0][0])[i] = (_Float16)0.0f;
        (&sh1[0][0][0][0][0])[i] = (_Float16)0.0f;
    }
    for (int i = tid; i < MB * TT; i += NTHR)
        sh_x[i >> 9][i & (TT - 1)] = x[(size_t)b0 * TT + i];
    for (int i = tid; i < HH; i += NTHR) sh_wfc[i] = W_fc[i];

    const bool hasT1 = (2 * w + 1 < 13);

    // ---- A fragments, both tiles. A-row r=n -> unit 4*tile+(n>>2), gate n&3.
    // k-map: k = ki*32 + q*8 + e (same bijection as B layout -> correct sums).
    f16x8 whh0[2][2], wih1[2][2], whh1[2][2];   // [tile][ki]
    #pragma unroll
    for (int tt = 0; tt < 2; ++tt) {
        int tile = 2 * w + tt;
        int ur   = 4 * tile + (n >> 2);
        bool rok = (ur < HH);
        int grow = (n & 3) * HH + (rok ? ur : 0);
        #pragma unroll
        for (int ki = 0; ki < 2; ++ki) {
            #pragma unroll
            for (int e = 0; e < 8; ++e) {
                int k = ki * 32 + q * 8 + e;
                bool ok = rok && (k < HH);
                whh0[tt][ki][e] = ok ? (_Float16)W_hh0[grow * HH + k] : (_Float16)0.0f;
                wih1[tt][ki][e] = ok ? (_Float16)W_ih1[grow * HH + k] : (_Float16)0.0f;
                whh1[tt][ki][e] = ok ? (_Float16)W_hh1[grow * HH + k] : (_Float16)0.0f;
            }
        }
    }

    // ---- chain identity ----
    const bool isL1 = (n & 4) != 0;
    const int  u    = 8 * w + ((n & 8) ? 4 : 0) + q;
    const int  cb   = n & 3;
    const bool wr   = (u < HH);
    const int  uc   = wr ? u : 0;

    float bza[4], wza[4];
    #pragma unroll
    for (int e = 0; e < 4; ++e) {
        int gr = e * HH + uc;
        bza[e] = isL1 ? (b_ih1[gr] + b_hh1[gr]) : (b_ih0[gr] + b_hh0[gr]);
        wza[e] = isL1 ? 0.0f : W_ih0[gr];
    }

    // write ptrs (this lane's h -> col cb and col cb+4 (+32 f16)); step P writes buf P^1
    const int uk = uc >> 5, uq2 = (uc >> 3) & 3, ue = uc & 7;
    _Float16* wp0 = isL1 ? &sh1[1][uk][uq2][cb][ue] : &sh0[1][uk][uq2][cb][ue];
    _Float16* wp1 = isL1 ? &sh1[0][uk][uq2][cb][ue] : &sh0[0][uk][uq2][cb][ue];

    const float* xq = &sh_x[cb][0];
    const f32x4 z = {0.0f, 0.0f, 0.0f, 0.0f};
    float cst = 0.0f;

    __syncthreads();

#define MFMA(A, B, C) __builtin_amdgcn_mfma_f32_16x16x32_f16((A), (B), (C), 0, 0, 0)

#define STEP(P, T0, XI)                                                           \
    {                                                                             \
        f16x8 hb0 = *(const f16x8*)&sh0[P][0][q][n][0];                           \
        f16x8 hb1 = *(const f16x8*)&sh0[P][1][q][n][0];                           \
        f16x8 pb0 = *(const f16x8*)&sh1[P][0][q][n][0];                           \
        f16x8 pb1 = *(const f16x8*)&sh1[P][1][q][n][0];                           \
        f32x4 a0A = MFMA(whh0[0][0], hb0, z);                                     \
        a0A = MFMA(whh0[0][1], hb1, a0A);                                         \
        f32x4 a1A = MFMA(wih1[0][0], hb0, z);                                     \
        a1A = MFMA(wih1[0][1], hb1, a1A);                                         \
        a1A = MFMA(whh1[0][0], pb0, a1A);                                         \
        a1A = MFMA(whh1[0][1], pb1, a1A);                                         \
        f32x4 a0B = z, a1B = z;                                                   \
        if (hasT1) {                                                              \
            a0B = MFMA(whh0[1][0], hb0, z);                                       \
            a0B = MFMA(whh0[1][1], hb1, a0B);                                     \
            a1B = MFMA(wih1[1][0], hb0, z);                                       \
            a1B = MFMA(wih1[1][1], hb1, a1B);                                     \
            a1B = MFMA(whh1[1][0], pb0, a1B);                                     \
            a1B = MFMA(whh1[1][1], pb1, a1B);                                     \
        }                                                                         \
        float xi = (XI);                                                          \
        float g[4];                                                               \
        _Pragma("unroll")                                                         \
        for (int e = 0; e < 4; ++e) {                                             \
            float own = isL1 ? a1A[e] : a0A[e];                                   \
            float pre = isL1 ? a1B[e] : a0B[e];                                   \
            float shm = __shfl_xor(pre, 8);                                       \
            g[e] = __builtin_fmaf(xi, wza[e], ((n & 8) ? shm : own) + bza[e]);    \
        }                                                                         \
        float eI = ex2_f(g[0] * -L2E);                                            \
        float eF = ex2_f(g[1] * -L2E);                                            \
        float tG = ex2_f(g[2] * (2.0f * L2E));                                    \
        float eO = ex2_f(g[3] * -L2E);                                            \
        float dI = 1.0f + eI, dF = 1.0f + eF, dO = 1.0f + eO;                     \
        float IG = (tG - 1.0f) * rcp_f(dI * (tG + 1.0f));                         \
        float cn = __builtin_fmaf(rcp_f(dF), cst, IG);                            \
        cst = ((T0) && isL1) ? 0.0f : cn;                                         \
        float cc = fminf(fmaxf(cst, -16.0f), 16.0f);                              \
        float tc = ex2_f(cc * (2.0f * L2E));                                      \
        float hv = (tc - 1.0f) * rcp_f(dO * (tc + 1.0f));                         \
        if (wr && !((T0) && isL1)) {                                              \
            _Float16 h16 = (_Float16)hv;                                          \
            _Float16* wp = (P) ? wp1 : wp0;                                       \
            wp[0]  = h16;                                                         \
            wp[32] = h16;                                                         \
        }                                                                         \
        __syncthreads();                                                          \
    }

    // t=0 (P=0): L1 chain suppressed (h1(-1) stays 0)
    STEP(0, 1, xq[0])
    // t=1..510: 255 (odd,even) pairs
    for (int k2 = 0; k2 < 255; ++k2) {
        STEP(1, 0, xq[1])
        STEP(0, 0, xq[2])
        xq += 2;
    }
    // t=511 (P=1): writes h0(511), h1(510) into buf 0
    STEP(1, 0, xq[1])
#undef STEP

    // ---- tail: h1(511) from h0(511), h1(510) (both buf 0) ----
    {
        f16x8 hb0 = *(const f16x8*)&sh0[0][0][q][n][0];
        f16x8 hb1 = *(const f16x8*)&sh0[0][1][q][n][0];
        f16x8 pb0 = *(const f16x8*)&sh1[0][0][q][n][0];
        f16x8 pb1 = *(const f16x8*)&sh1[0][1][q][n][0];
        f32x4 a1A = MFMA(wih1[0][0], hb0, z);
        a1A = MFMA(wih1[0][1], hb1, a1A);
        a1A = MFMA(whh1[0][0], pb0, a1A);
        a1A = MFMA(whh1[0][1], pb1, a1A);
        f32x4 a1B = z;
        if (hasT1) {
            a1B = MFMA(wih1[1][0], hb0, z);
            a1B = MFMA(wih1[1][1], hb1, a1B);
            a1B = MFMA(whh1[1][0], pb0, a1B);
            a1B = MFMA(whh1[1][1], pb1, a1B);
        }
        float g[4];
        #pragma unroll
        for (int e = 0; e < 4; ++e) {
            float shm = __shfl_xor(a1B[e], 8);
            g[e] = ((n & 8) ? shm : a1A[e]) + bza[e];
        }
        if (isL1 && wr) {
            float eI = ex2_f(g[0] * -L2E);
            float eF = ex2_f(g[1] * -L2E);
            float tG = ex2_f(g[2] * (2.0f * L2E));
            float eO = ex2_f(g[3] * -L2E);
            float dI = 1.0f + eI, dF = 1.0f + eF, dO = 1.0f + eO;
            float IG = (tG - 1.0f) * rcp_f(dI * (tG + 1.0f));
            float cn = __builtin_fmaf(rcp_f(dF), cst, IG);
            float cc = fminf(fmaxf(cn, -16.0f), 16.0f);
            float tc = ex2_f(cc * (2.0f * L2E));
            shf[cb][uc] = (tc - 1.0f) * rcp_f(dO * (tc + 1.0f));
        }
    }
    __syncthreads();

    if (tid < MB) {
        float s = b_fc[0];
        for (int j = 0; j < HH; ++j) s += shf[tid][j] * sh_wfc[j];
        out[b0 + tid] = s;
    }
#undef MFMA
}

extern "C" void kernel_launch(void* const* d_in, const int* in_sizes, int n_in,
                              void* d_out, int out_size, void* d_ws, size_t ws_size,
                              hipStream_t stream) {
    const float* xin   = (const float*)d_in[0];
    const float* W_ih0 = (const float*)d_in[1];
    const float* W_hh0 = (const float*)d_in[2];
    const float* b_ih0 = (const float*)d_in[3];
    const float* b_hh0 = (const float*)d_in[4];
    const float* W_ih1 = (const float*)d_in[5];
    const float* W_hh1 = (const float*)d_in[6];
    const float* b_ih1 = (const float*)d_in[7];
    const float* b_hh1 = (const float*)d_in[8];
    const float* W_fc  = (const float*)d_in[9];
    const float* b_fc  = (const float*)d_in[10];
    float* out = (float*)d_out;

    lstm2_kernel<<<dim3(2048 / MB), dim3(NTHR), 0, stream>>>(
        xin, W_ih0, W_hh0, b_ih0, b_hh0, W_ih1, W_hh1, b_ih1, b_hh1, W_fc, b_fc, out);
}

// Round 6
// 258.290 us; speedup vs baseline: 1.4525x; 1.4525x over previous
//
#include <hip/hip_runtime.h>

#define TT   512
#define HH   50
#define MB   8            // batch rows per block
#define NW   13           // waves per block
#define NTHR (NW * 64)    // 832 threads

typedef _Float16 f16x8 __attribute__((ext_vector_type(8)));
typedef float    f32x4 __attribute__((ext_vector_type(4)));

#define L2E 1.4426950408889634f

__device__ __forceinline__ float rcp_f(float v) { return __builtin_amdgcn_rcpf(v); }
__device__ __forceinline__ float ex2_f(float v) { return __builtin_amdgcn_exp2f(v); }

// 13 waves, grid 256. Wave w owns gate-tile w (units 4w..4w+3, A-rows interleaved
// i,f,g,o per unit). Lane (q=l>>4, n=l&15): acc[e] = gate e of unit u=4w+q, col n.
// h0 is stored at cols 0-7 AND copied to cols 8-15; h1 lives only at cols 8-15.
// So a0 cols 0-7 = L0 gates (batch n), a1 cols 8-15 = L1 gates (batch n-8):
// lanes n<8 run the L0 chain, lanes n>=8 run L1 — no shuffles, one cndmask per e.
// One barrier per step; layer 1 pipelined one step behind layer 0.
// Weights/biases pre-scaled by -log2e (i,f,o) / +2log2e (g) so exp2 args are direct.
__global__ __launch_bounds__(NTHR, 1)
void lstm2_kernel(const float* __restrict__ x,
                  const float* __restrict__ W_ih0, const float* __restrict__ W_hh0,
                  const float* __restrict__ b_ih0, const float* __restrict__ b_hh0,
                  const float* __restrict__ W_ih1, const float* __restrict__ W_hh1,
                  const float* __restrict__ b_ih1, const float* __restrict__ b_hh1,
                  const float* __restrict__ W_fc,  const float* __restrict__ b_fc,
                  float* __restrict__ out)
{
    // h layout [parity][ki][q][col][e] f16; unit u -> (ki=u>>5, q=(u>>3)&3, e=u&7).
    // Lane (q,n) B-frag read at [P][ki][q][n][0..7] = addr l*16B: fully linear.
    __shared__ __align__(16) _Float16 sh0[2][2][4][16][8];   // h0 (cols 0-7 + copy 8-15)
    __shared__ __align__(16) _Float16 sh1[2][2][4][16][8];   // h1 (cols 8-15; 0-7 stay 0)
    __shared__ float sh_x[MB][TT + 4];
    __shared__ float shf[MB][52];
    __shared__ float sh_wfc[HH];

    const int tid = threadIdx.x;
    const int w   = tid >> 6;
    const int l   = tid & 63;
    const int q   = l >> 4;
    const int n   = l & 15;
    const int b0  = blockIdx.x * MB;

    for (int i = tid; i < 2 * 2 * 4 * 16 * 8; i += NTHR) {
        (&sh0[0][0][0][0][0])[i] = (_Float16)0.0f;
        (&sh1[0][0][0][0][0])[i] = (_Float16)0.0f;
    }
    for (int i = tid; i < MB * TT; i += NTHR)
        sh_x[i >> 9][i & (TT - 1)] = x[(size_t)b0 * TT + i];
    for (int i = tid; i < HH; i += NTHR) sh_wfc[i] = W_fc[i];

    // ---- A fragments (weights), gate-scaled. A-row r=n -> unit 4w+(n>>2), gate n&3,
    // weight row grow = (n&3)*HH + u_r. k-map: k = ki*32 + q*8 + e (same bijection
    // as the B layout -> sums correct).
    const int  u_r   = w * 4 + (n >> 2);
    const bool rowok = (u_r < HH);
    const int  grow  = (n & 3) * HH + (rowok ? u_r : 0);
    const float srow = ((n & 3) == 2) ? (2.0f * L2E) : (-L2E);

    f16x8 whh0[2], wih1[2], whh1[2];
    #pragma unroll
    for (int ki = 0; ki < 2; ++ki) {
        #pragma unroll
        for (int e = 0; e < 8; ++e) {
            int k = ki * 32 + q * 8 + e;
            bool ok = rowok && (k < HH);
            whh0[ki][e] = ok ? (_Float16)(srow * W_hh0[grow * HH + k]) : (_Float16)0.0f;
            wih1[ki][e] = ok ? (_Float16)(srow * W_ih1[grow * HH + k]) : (_Float16)0.0f;
            whh1[ki][e] = ok ? (_Float16)(srow * W_hh1[grow * HH + k]) : (_Float16)0.0f;
        }
    }

    // ---- chain identity: lane n<8 = L0 batch n; lane n>=8 = L1 batch n-8 ----
    const bool isL1 = (n >= 8);
    const int  u    = 4 * w + q;
    const int  cb   = n & 7;
    const bool wr   = (u < HH);
    const int  uc   = wr ? u : 0;

    float bza[4], wza[4];
    #pragma unroll
    for (int e = 0; e < 4; ++e) {
        int gr = e * HH + uc;
        float sc = (e == 2) ? (2.0f * L2E) : (-L2E);
        bza[e] = sc * (isL1 ? (b_ih1[gr] + b_hh1[gr]) : (b_ih0[gr] + b_hh0[gr]));
        wza[e] = isL1 ? 0.0f : (sc * W_ih0[gr]);
    }

    // write ptrs: L0 lane -> sh0[buf][...][cb] (+ copy at col cb+8 = +64 f16);
    //             L1 lane -> sh1[buf][...][cb+8]. Step P writes buf P^1.
    const int uk = uc >> 5, uq2 = (uc >> 3) & 3, ue = uc & 7;
    _Float16* wpA0 = isL1 ? &sh1[1][uk][uq2][cb + 8][ue] : &sh0[1][uk][uq2][cb][ue];
    _Float16* wpA1 = isL1 ? &sh1[0][uk][uq2][cb + 8][ue] : &sh0[0][uk][uq2][cb][ue];

    const float* xq = &sh_x[cb][0];
    const f32x4 z = {0.0f, 0.0f, 0.0f, 0.0f};
    float cst = 0.0f;

    __syncthreads();

#define MFMA(A, B, C) __builtin_amdgcn_mfma_f32_16x16x32_f16((A), (B), (C), 0, 0, 0)

#define STEP(P, T0, XI)                                                           \
    {                                                                             \
        f16x8 hb0 = *(const f16x8*)&sh0[P][0][q][n][0];                           \
        f16x8 hb1 = *(const f16x8*)&sh0[P][1][q][n][0];                           \
        f16x8 pb0 = *(const f16x8*)&sh1[P][0][q][n][0];                           \
        f16x8 pb1 = *(const f16x8*)&sh1[P][1][q][n][0];                           \
        f32x4 a0 = MFMA(whh0[0], hb0, z);                                         \
        a0 = MFMA(whh0[1], hb1, a0);                                              \
        f32x4 a1 = MFMA(wih1[0], hb0, z);                                         \
        a1 = MFMA(wih1[1], hb1, a1);                                              \
        a1 = MFMA(whh1[0], pb0, a1);                                              \
        a1 = MFMA(whh1[1], pb1, a1);                                              \
        float xi = (XI);                                                          \
        float g0 = (isL1 ? a1[0] : a0[0]) + bza[0];                               \
        float g1 = (isL1 ? a1[1] : a0[1]) + bza[1];                               \
        float g2 = (isL1 ? a1[2] : a0[2]) + bza[2];                               \
        float g3 = (isL1 ? a1[3] : a0[3]) + bza[3];                               \
        g0 = __builtin_fmaf(xi, wza[0], g0);                                      \
        g1 = __builtin_fmaf(xi, wza[1], g1);                                      \
        g2 = __builtin_fmaf(xi, wza[2], g2);                                      \
        g3 = __builtin_fmaf(xi, wza[3], g3);                                      \
        float eI = ex2_f(g0), eF = ex2_f(g1), tG = ex2_f(g2), eO = ex2_f(g3);     \
        float dI = 1.0f + eI, dF = 1.0f + eF, dO = 1.0f + eO;                     \
        float IG = (tG - 1.0f) * rcp_f(dI * (tG + 1.0f));                         \
        float cn = __builtin_fmaf(rcp_f(dF), cst, IG);                            \
        cst = ((T0) && isL1) ? 0.0f : cn;                                         \
        float cc = fminf(fmaxf(cst, -16.0f), 16.0f);                              \
        float tc = ex2_f(cc * (2.0f * L2E));                                      \
        float hv = (tc - 1.0f) * rcp_f(dO * (tc + 1.0f));                         \
        if (wr && !((T0) && isL1)) {                                              \
            _Float16 h16 = (_Float16)hv;                                          \
            _Float16* wp = (P) ? wpA1 : wpA0;                                     \
            wp[0] = h16;                                                          \
            if (!isL1) wp[64] = h16;   /* h0 copy at col cb+8 */                  \
        }                                                                         \
        __syncthreads();                                                          \
    }

    // t=0 (P=0): L1 chain suppressed (h1(-1) stays 0)
    STEP(0, 1, xq[0])
    // t=1..510: 255 (odd,even) pairs
    for (int k2 = 0; k2 < 255; ++k2) {
        STEP(1, 0, xq[1])
        STEP(0, 0, xq[2])
        xq += 2;
    }
    // t=511 (P=1): writes h0(511), h1(510) into buf 0
    STEP(1, 0, xq[1])
#undef STEP

    // ---- tail: h1(511) from h0(511), h1(510) (both in buf 0) ----
    {
        f16x8 hb0 = *(const f16x8*)&sh0[0][0][q][n][0];
        f16x8 hb1 = *(const f16x8*)&sh0[0][1][q][n][0];
        f16x8 pb0 = *(const f16x8*)&sh1[0][0][q][n][0];
        f16x8 pb1 = *(const f16x8*)&sh1[0][1][q][n][0];
        f32x4 a1 = MFMA(wih1[0], hb0, z);
        a1 = MFMA(wih1[1], hb1, a1);
        a1 = MFMA(whh1[0], pb0, a1);
        a1 = MFMA(whh1[1], pb1, a1);
        if (isL1 && wr) {
            float g0 = a1[0] + bza[0];
            float g1 = a1[1] + bza[1];
            float g2 = a1[2] + bza[2];
            float g3 = a1[3] + bza[3];
            float eI = ex2_f(g0), eF = ex2_f(g1), tG = ex2_f(g2), eO = ex2_f(g3);
            float dI = 1.0f + eI, dF = 1.0f + eF, dO = 1.0f + eO;
            float IG = (tG - 1.0f) * rcp_f(dI * (tG + 1.0f));
            float cn = __builtin_fmaf(rcp_f(dF), cst, IG);
            float cc = fminf(fmaxf(cn, -16.0f), 16.0f);
            float tc = ex2_f(cc * (2.0f * L2E));
            shf[cb][uc] = (tc - 1.0f) * rcp_f(dO * (tc + 1.0f));
        }
    }
    __syncthreads();

    if (tid < MB) {
        float s = b_fc[0];
        for (int j = 0; j < HH; ++j) s += shf[tid][j] * sh_wfc[j];
        out[b0 + tid] = s;
    }
#undef MFMA
}

extern "C" void kernel_launch(void* const* d_in, const int* in_sizes, int n_in,
                              void* d_out, int out_size, void* d_ws, size_t ws_size,
                              hipStream_t stream) {
    const float* xin   = (const float*)d_in[0];
    const float* W_ih0 = (const float*)d_in[1];
    const float* W_hh0 = (const float*)d_in[2];
    const float* b_ih0 = (const float*)d_in[3];
    const float* b_hh0 = (const float*)d_in[4];
    const float* W_ih1 = (const float*)d_in[5];
    const float* W_hh1 = (const float*)d_in[6];
    const float* b_ih1 = (const float*)d_in[7];
    const float* b_hh1 = (const float*)d_in[8];
    const float* W_fc  = (const float*)d_in[9];
    const float* b_fc  = (const float*)d_in[10];
    float* out = (float*)d_out;

    lstm2_kernel<<<dim3(2048 / MB), dim3(NTHR), 0, stream>>>(
        xin, W_ih0, W_hh0, b_ih0, b_hh0, W_ih1, W_hh1, b_ih1, b_hh1, W_fc, b_fc, out);
}